// Round 8
// baseline (324.144 us; speedup 1.0000x reference)
//
#include <hip/hip_runtime.h>

#define Bsz 2
#define Sq  4096
#define Dm  1024
#define NH  16
#define HD  64

typedef __attribute__((ext_vector_type(8))) short short8;   // 8 bf16 = 4 VGPRs
typedef __attribute__((ext_vector_type(4))) float f32x4;
typedef __attribute__((ext_vector_type(2))) __fp16 fp16x2;  // cvt_pkrtz result type
typedef __attribute__((ext_vector_type(4))) _Float16 half4v;
typedef __attribute__((ext_vector_type(8))) _Float16 half8v; // K=32 f16 MFMA operand

__device__ __forceinline__ unsigned short f2bf(float x) {
    unsigned int u = __float_as_uint(x);
    u += 0x7fffu + ((u >> 16) & 1u);            // round-to-nearest-even
    return (unsigned short)(u >> 16);
}

__device__ __forceinline__ void gl2lds16(const unsigned short* g, unsigned short* l) {
    __builtin_amdgcn_global_load_lds(
        (const __attribute__((address_space(1))) unsigned int*)g,
        (__attribute__((address_space(3))) unsigned int*)l, 16, 0, 0);
}

// ---------------------------------------------------------------------------
// fp32 -> bf16 bulk convert (X). 4 elems/thread.
// ---------------------------------------------------------------------------
__global__ __launch_bounds__(256) void cvt_bf16(const float4* __restrict__ in,
                                                ushort4* __restrict__ out) {
    const int i = blockIdx.x * 256 + threadIdx.x;
    const float4 v = in[i];
    ushort4 r;
    r.x = f2bf(v.x); r.y = f2bf(v.y); r.z = f2bf(v.z); r.w = f2bf(v.w);
    out[i] = r;
}

// ---------------------------------------------------------------------------
// Fused weight transpose: W[K][N] fp32 -> WtAll[z][N][K] bf16, z in {q,k,v,o}
// ---------------------------------------------------------------------------
__global__ __launch_bounds__(256) void wtrans4(const float* __restrict__ Wq,
                                               const float* __restrict__ Wk,
                                               const float* __restrict__ Wv,
                                               const float* __restrict__ Wo,
                                               unsigned short* __restrict__ WtAll) {
    __shared__ float tile[64][65];
    const int z = blockIdx.z;
    const float* W = (z == 0) ? Wq : (z == 1) ? Wk : (z == 2) ? Wv : Wo;
    unsigned short* Wt = WtAll + (size_t)z * Dm * Dm;
    const int k0 = blockIdx.y * 64, n0 = blockIdx.x * 64;
    const int t = threadIdx.x;
    #pragma unroll
    for (int i = 0; i < 16; ++i) {
        const int idx = t + i * 256, r = idx >> 6, c = idx & 63;
        tile[r][c] = W[(size_t)(k0 + r) * Dm + n0 + c];
    }
    __syncthreads();
    #pragma unroll
    for (int i = 0; i < 16; ++i) {
        const int idx = t + i * 256, rr = idx >> 6, cc = idx & 63;
        Wt[(size_t)(n0 + rr) * Dm + k0 + cc] = f2bf(tile[cc][rr]);
    }
}

// ===========================================================================
// Shared GEMM core: 128x128 tile, BK=32, bf16 MFMA, global_load_lds staging.
// ===========================================================================
struct GemmCtx {
    int wm, wn, quad, c16;
    f32x4 acc[4][4];
};

__device__ __forceinline__ void gemm_core(
    const unsigned short* __restrict__ A,
    const unsigned short* __restrict__ Bt,
    int bm, int bn, unsigned short* As, unsigned short* Bs, GemmCtx& cx)
{
    const int t    = threadIdx.x;
    const int w    = t >> 6;
    const int lane = t & 63;
    cx.quad = lane >> 4;
    cx.c16  = lane & 15;
    cx.wm = (w >> 1) * 64;
    cx.wn = (w & 1) * 64;

    #pragma unroll
    for (int i = 0; i < 4; ++i)
        #pragma unroll
        for (int j = 0; j < 4; ++j)
            cx.acc[i][j] = (f32x4){0.f, 0.f, 0.f, 0.f};

    const int srow = lane >> 2, soff = (lane & 3) * 8;
    const unsigned short* Ag0 = A  + (size_t)(bm + w * 16 + srow) * Dm + soff;
    const unsigned short* Ag1 = Ag0 + (size_t)64 * Dm;
    const unsigned short* Bg0 = Bt + (size_t)(bn + w * 16 + srow) * Dm + soff;
    const unsigned short* Bg1 = Bg0 + (size_t)64 * Dm;
    unsigned short* Al0 = As + (w * 16) * 32;
    unsigned short* Al1 = As + (64 + w * 16) * 32;
    unsigned short* Bl0 = Bs + (w * 16) * 32;
    unsigned short* Bl1 = Bs + (64 + w * 16) * 32;

    for (int k0 = 0; k0 < Dm; k0 += 32) {
        __syncthreads();
        gl2lds16(Ag0 + k0, Al0);
        gl2lds16(Ag1 + k0, Al1);
        gl2lds16(Bg0 + k0, Bl0);
        gl2lds16(Bg1 + k0, Bl1);
        __syncthreads();

        short8 af[4], bf[4];
        #pragma unroll
        for (int mt = 0; mt < 4; ++mt)
            af[mt] = *(const short8*)(As + (cx.wm + mt * 16 + cx.c16) * 32 + cx.quad * 8);
        #pragma unroll
        for (int nt = 0; nt < 4; ++nt)
            bf[nt] = *(const short8*)(Bs + (cx.wn + nt * 16 + cx.c16) * 32 + cx.quad * 8);
        #pragma unroll
        for (int mt = 0; mt < 4; ++mt)
            #pragma unroll
            for (int nt = 0; nt < 4; ++nt)
                cx.acc[mt][nt] = __builtin_amdgcn_mfma_f32_16x16x32_bf16(
                    af[mt], bf[nt], cx.acc[mt][nt], 0, 0, 0);
    }
}

// ---------------------------------------------------------------------------
// Fused QKV projection: A=Xb[8192,1024], Bt=WtAll (Wq|Wk|Wv rows, 3072x1024).
// ---------------------------------------------------------------------------
__global__ __launch_bounds__(256) void gemm_qkv(
    const unsigned short* __restrict__ A,
    const unsigned short* __restrict__ WtAll,
    const float* __restrict__ bq, const float* __restrict__ bk,
    const float* __restrict__ bv,
    unsigned short* __restrict__ Qh, unsigned short* __restrict__ Kh,
    unsigned short* __restrict__ Vt, float qscale)
{
    __shared__ unsigned short As[128 * 32];
    __shared__ unsigned short Bs[128 * 32];
    const int bm = blockIdx.y * 128;
    const int bn = blockIdx.x * 128;          // 0..3072
    GemmCtx cx;
    gemm_core(A, WtAll, bm, bn, As, Bs, cx);

    const int which = bn >> 10;               // 0=Q 1=K 2=V
    const float* bias = (which == 0) ? bq : (which == 1) ? bk : bv;
    const float osc = (which == 0) ? qscale : 1.0f;

    #pragma unroll
    for (int mt = 0; mt < 4; ++mt) {
        const int m0 = bm + cx.wm + mt * 16 + cx.quad * 4;
        #pragma unroll
        for (int nt = 0; nt < 4; ++nt) {
            const int n  = bn + cx.wn + nt * 16 + cx.c16;
            const int nl = n & 1023;
            const float bvv = bias[nl];
            const int h = (nl >> 6), d = nl & 63;
            if (which < 2) {
                unsigned short* C = (which == 0) ? Qh : Kh;
                #pragma unroll
                for (int r = 0; r < 4; ++r) {
                    const int m = m0 + r;
                    const int b = m >> 12, s = m & (Sq - 1);
                    C[((size_t)(b * NH + h) * Sq + s) * HD + d] =
                        f2bf((cx.acc[mt][nt][r] + bvv) * osc);
                }
            } else {
                const int b = m0 >> 12, s0 = m0 & (Sq - 1);
                union { fp16x2 h2[2]; unsigned int u[2]; } pk;
                pk.h2[0] = __builtin_amdgcn_cvt_pkrtz(cx.acc[mt][nt][0] + bvv,
                                                      cx.acc[mt][nt][1] + bvv);
                pk.h2[1] = __builtin_amdgcn_cvt_pkrtz(cx.acc[mt][nt][2] + bvv,
                                                      cx.acc[mt][nt][3] + bvv);
                *(uint2*)(Vt + ((size_t)(b * NH + h) * HD + d) * Sq + s0) =
                    make_uint2(pk.u[0], pk.u[1]);
            }
        }
    }
}

// ---------------------------------------------------------------------------
// Output projection: fp32 out = AO @ Wo^T + bo
// ---------------------------------------------------------------------------
__global__ __launch_bounds__(256) void gemm_o(
    const unsigned short* __restrict__ A,
    const unsigned short* __restrict__ Bt,
    const float* __restrict__ bias, float* __restrict__ C)
{
    __shared__ unsigned short As[128 * 32];
    __shared__ unsigned short Bs[128 * 32];
    const int bm = blockIdx.y * 128;
    const int bn = blockIdx.x * 128;
    GemmCtx cx;
    gemm_core(A, Bt, bm, bn, As, Bs, cx);

    #pragma unroll
    for (int mt = 0; mt < 4; ++mt) {
        const int m0 = bm + cx.wm + mt * 16 + cx.quad * 4;
        #pragma unroll
        for (int nt = 0; nt < 4; ++nt) {
            const int n = bn + cx.wn + nt * 16 + cx.c16;
            const float bvv = bias[n];
            #pragma unroll
            for (int r = 0; r < 4; ++r)
                C[(size_t)(m0 + r) * Dm + n] = cx.acc[mt][nt][r] + bvv;
        }
    }
}

// ---------------------------------------------------------------------------
// Flash attention v6: v5 + software-pipelined ktile body so MFMA bursts and
// VALU bursts are mutually independent neighbors (QK nt23 || exp nt01,
// PV cc0 || exp nt23) — breaks the wave phase-lock that serialized the pipes.
// P packs directly into K=32 operands via union (no concat moves).
// ---------------------------------------------------------------------------
__global__ __launch_bounds__(256, 2) void attn_mfma6(
    const unsigned short* __restrict__ Q,
    const unsigned short* __restrict__ K,
    const unsigned short* __restrict__ Vt,
    unsigned short* __restrict__ AO)
{
    __shared__ unsigned short Ks[2][64 * 72];   // [key][d] bf16, padded rows
    __shared__ unsigned short Vs[2][64 * 72];   // [d][pos] fp16, key-permuted

    const int qt = blockIdx.x;                // 0..15 (256 queries each)
    const int bh = blockIdx.y;                // 0..31
    const int b = bh >> 4, h = bh & 15;
    const int t    = threadIdx.x;
    const int w    = t >> 6;
    const int lane = t & 63;
    const int quad = lane >> 4;
    const int c16  = lane & 15;
    const size_t base = (size_t)bh * Sq * HD;
    const int NT = Sq / 64;

    // Q B-frags: 4 query-groups x 2 k-halves, held all kernel
    short8 qf[4][2];
    #pragma unroll
    for (int qg = 0; qg < 4; ++qg) {
        const unsigned short* qp =
            Q + base + (size_t)(qt * 256 + w * 64 + qg * 16 + c16) * HD;
        qf[qg][0] = *(const short8*)(qp + quad * 8);
        qf[qg][1] = *(const short8*)(qp + 32 + quad * 8);
    }

    f32x4 O[4][4];                 // [qg][d-group]
    f32x4 Lsum[4];
    #pragma unroll
    for (int qg = 0; qg < 4; ++qg) {
        Lsum[qg] = (f32x4){0.f, 0.f, 0.f, 0.f};
        #pragma unroll
        for (int g = 0; g < 4; ++g)
            O[qg][g] = (f32x4){0.f, 0.f, 0.f, 0.f};
    }
    half8v ones8;
    #pragma unroll
    for (int i = 0; i < 8; ++i) ones8[i] = (_Float16)1.f;

    // staging geometry: row = t>>2 (0..63), chunk = (t&3)*8 halfwords
    const int srow = t >> 2, sc4 = (t & 3) * 8;
    // V key-permutation for 4-key subchunks (within 32-key group)
    const int f0 = (sc4 < 16) ? sc4 * 2 : (sc4 - 16) * 2 + 4;           // {0,16,4,20}
    const int f1 = (sc4 + 4 < 16) ? (sc4 + 4) * 2 : (sc4 - 12) * 2 + 4; // {8,24,12,28}

    const unsigned short* kg = K  + base + (size_t)srow * HD + sc4;
    const unsigned short* vg = Vt + base + (size_t)srow * Sq + sc4;
    unsigned short* ksl = &Ks[0][0] + srow * 72 + sc4;
    unsigned short* vsl = &Vs[0][0] + srow * 72;          // + permuted pos
    const int LBUF = 64 * 72;

    int4 kr0, kr1, vr0, vr1;
    kr0 = *(const int4*)(kg);
    kr1 = *(const int4*)(kg + 32);
    vr0 = *(const int4*)(vg);
    vr1 = *(const int4*)(vg + 32);
    *(int4*)(ksl)      = kr0;
    *(int4*)(ksl + 32) = kr1;
    *(uint2*)(vsl + f0)      = make_uint2(vr0.x, vr0.y);
    *(uint2*)(vsl + f1)      = make_uint2(vr0.z, vr0.w);
    *(uint2*)(vsl + 32 + f0) = make_uint2(vr1.x, vr1.y);
    *(uint2*)(vsl + 32 + f1) = make_uint2(vr1.z, vr1.w);

    for (int kt = 0; kt < NT; ++kt) {
        const int cur = kt & 1;
        const bool more = (kt + 1 < NT);
        if (more) {                           // prefetch next tile into regs
            const unsigned short* kp = kg + (size_t)(kt + 1) * 64 * HD;
            const unsigned short* vp = vg + (kt + 1) * 64;
            kr0 = *(const int4*)(kp);
            kr1 = *(const int4*)(kp + 32);
            vr0 = *(const int4*)(vp);
            vr1 = *(const int4*)(vp + 32);
        }
        __syncthreads();

        const unsigned short* ksb = &Ks[cur][0];
        const unsigned short* vsb = &Vs[cur][0];

        union PU { half4v h4[2]; half8v h8; };
        PU P32[4][2];             // [qg][cc]
        f32x4 z01[4][2], z23[4][2];

        // --- Phase 1: QK for nt=0,1 (16 MFMA) ---
        #pragma unroll
        for (int nt = 0; nt < 2; ++nt) {
            const int krow = nt * 16 + c16;
            const short8 kf0 = *(const short8*)(ksb + krow * 72 + quad * 8);
            const short8 kf1 = *(const short8*)(ksb + krow * 72 + 32 + quad * 8);
            #pragma unroll
            for (int qg = 0; qg < 4; ++qg) {
                f32x4 z = (f32x4){0.f, 0.f, 0.f, 0.f};
                z = __builtin_amdgcn_mfma_f32_16x16x32_bf16(kf0, qf[qg][0], z, 0, 0, 0);
                z01[qg][nt] = __builtin_amdgcn_mfma_f32_16x16x32_bf16(
                    kf1, qf[qg][1], z, 0, 0, 0);
            }
        }

        // --- Phase 2: write prefetched tile to other buffer (LDS, no barrier
        //     needed: all waves finished reading nb at the top barrier) ---
        if (more) {
            const int nb = cur ^ 1;
            *(int4*)(ksl + nb * LBUF)      = kr0;
            *(int4*)(ksl + nb * LBUF + 32) = kr1;
            unsigned short* vdst = vsl + nb * LBUF;
            *(uint2*)(vdst + f0)      = make_uint2(vr0.x, vr0.y);
            *(uint2*)(vdst + f1)      = make_uint2(vr0.z, vr0.w);
            *(uint2*)(vdst + 32 + f0) = make_uint2(vr1.x, vr1.y);
            *(uint2*)(vdst + 32 + f1) = make_uint2(vr1.z, vr1.w);
        }

        // --- Phase 3: QK for nt=2,3 (16 MFMA) — independent of Phase 4 ---
        #pragma unroll
        for (int nt = 0; nt < 2; ++nt) {
            const int krow = (nt + 2) * 16 + c16;
            const short8 kf0 = *(const short8*)(ksb + krow * 72 + quad * 8);
            const short8 kf1 = *(const short8*)(ksb + krow * 72 + 32 + quad * 8);
            #pragma unroll
            for (int qg = 0; qg < 4; ++qg) {
                f32x4 z = (f32x4){0.f, 0.f, 0.f, 0.f};
                z = __builtin_amdgcn_mfma_f32_16x16x32_bf16(kf0, qf[qg][0], z, 0, 0, 0);
                z23[qg][nt] = __builtin_amdgcn_mfma_f32_16x16x32_bf16(
                    kf1, qf[qg][1], z, 0, 0, 0);
            }
        }

        // --- Phase 4: exp/pack nt=0,1 (VALU) — co-schedules with Phase 3 ---
        #pragma unroll
        for (int nt = 0; nt < 2; ++nt)
            #pragma unroll
            for (int qg = 0; qg < 4; ++qg) {
                const f32x4 z = z01[qg][nt];
                const float p0 = __builtin_amdgcn_exp2f(z[0]);
                const float p1 = __builtin_amdgcn_exp2f(z[1]);
                const float p2 = __builtin_amdgcn_exp2f(z[2]);
                const float p3 = __builtin_amdgcn_exp2f(z[3]);
                union { fp16x2 h2[2]; half4v h4; } pk;
                pk.h2[0] = __builtin_amdgcn_cvt_pkrtz(p0, p1);
                pk.h2[1] = __builtin_amdgcn_cvt_pkrtz(p2, p3);
                P32[qg][0].h4[nt] = pk.h4;
            }

        // --- Phase 5: PV cc=0 (20 MFMA) — co-schedules with Phase 6 ---
        #pragma unroll
        for (int g = 0; g < 4; ++g) {
            const half8v vf = *(const half8v*)
                (vsb + (g * 16 + c16) * 72 + quad * 8);
            #pragma unroll
            for (int qg = 0; qg < 4; ++qg)
                O[qg][g] = __builtin_amdgcn_mfma_f32_16x16x32_f16(
                    P32[qg][0].h8, vf, O[qg][g], 0, 0, 0);
        }
        #pragma unroll
        for (int qg = 0; qg < 4; ++qg)
            Lsum[qg] = __builtin_amdgcn_mfma_f32_16x16x32_f16(
                P32[qg][0].h8, ones8, Lsum[qg], 0, 0, 0);

        // --- Phase 6: exp/pack nt=2,3 (VALU) ---
        #pragma unroll
        for (int nt = 0; nt < 2; ++nt)
            #pragma unroll
            for (int qg = 0; qg < 4; ++qg) {
                const f32x4 z = z23[qg][nt];
                const float p0 = __builtin_amdgcn_exp2f(z[0]);
                const float p1 = __builtin_amdgcn_exp2f(z[1]);
                const float p2 = __builtin_amdgcn_exp2f(z[2]);
                const float p3 = __builtin_amdgcn_exp2f(z[3]);
                union { fp16x2 h2[2]; half4v h4; } pk;
                pk.h2[0] = __builtin_amdgcn_cvt_pkrtz(p0, p1);
                pk.h2[1] = __builtin_amdgcn_cvt_pkrtz(p2, p3);
                P32[qg][1].h4[nt] = pk.h4;
            }

        // --- Phase 7: PV cc=1 (20 MFMA) ---
        #pragma unroll
        for (int g = 0; g < 4; ++g) {
            const half8v vf = *(const half8v*)
                (vsb + (g * 16 + c16) * 72 + 32 + quad * 8);
            #pragma unroll
            for (int qg = 0; qg < 4; ++qg)
                O[qg][g] = __builtin_amdgcn_mfma_f32_16x16x32_f16(
                    P32[qg][1].h8, vf, O[qg][g], 0, 0, 0);
        }
        #pragma unroll
        for (int qg = 0; qg < 4; ++qg)
            Lsum[qg] = __builtin_amdgcn_mfma_f32_16x16x32_f16(
                P32[qg][1].h8, ones8, Lsum[qg], 0, 0, 0);
    }

    // finalize: Lsum per-lane (all c16 identical); store
    #pragma unroll
    for (int qg = 0; qg < 4; ++qg) {
        float linv[4];
        #pragma unroll
        for (int r = 0; r < 4; ++r) linv[r] = 1.f / Lsum[qg][r];
        #pragma unroll
        for (int g = 0; g < 4; ++g) {
            const int col = h * HD + g * 16 + c16;
            #pragma unroll
            for (int r = 0; r < 4; ++r) {
                const int s = qt * 256 + w * 64 + qg * 16 + quad * 4 + r;
                AO[((size_t)(b * Sq + s)) * Dm + col] = f2bf(O[qg][g][r] * linv[r]);
            }
        }
    }
}

// ---------------------------------------------------------------------------
extern "C" void kernel_launch(void* const* d_in, const int* in_sizes, int n_in,
                              void* d_out, int out_size, void* d_ws, size_t ws_size,
                              hipStream_t stream)
{
    const float* X  = (const float*)d_in[0];
    const float* Wq = (const float*)d_in[1];
    const float* bq = (const float*)d_in[2];
    const float* Wk = (const float*)d_in[3];
    const float* bk = (const float*)d_in[4];
    const float* Wv = (const float*)d_in[5];
    const float* bv = (const float*)d_in[6];
    const float* Wo = (const float*)d_in[7];
    const float* bo = (const float*)d_in[8];
    float* out = (float*)d_out;

    unsigned short* ws = (unsigned short*)d_ws;
    const size_t NX = (size_t)Bsz * Sq * Dm;   // 8,388,608
    const size_t NW = (size_t)Dm * Dm;         // 1,048,576
    unsigned short* Xb    = ws; ws += NX;
    unsigned short* WtAll = ws; ws += 4 * NW;  // [Wq|Wk|Wv|Wo] transposed bf16
    unsigned short* Qh    = ws; ws += NX;
    unsigned short* Kh    = ws; ws += NX;
    unsigned short* Vt    = ws; ws += NX;
    unsigned short* AO    = ws; ws += NX;

    cvt_bf16<<<(int)(NX / 1024), 256, 0, stream>>>((const float4*)X, (ushort4*)Xb);
    wtrans4<<<dim3(16, 16, 4), 256, 0, stream>>>(Wq, Wk, Wv, Wo, WtAll);

    const float SCL = 0.18033688011112042f;    // 0.125 * log2(e)
    gemm_qkv<<<dim3(3 * Dm / 128, (Bsz * Sq) / 128), 256, 0, stream>>>(
        Xb, WtAll, bq, bk, bv, Qh, Kh, Vt, SCL);

    attn_mfma6<<<dim3(Sq / 256, Bsz * NH), 256, 0, stream>>>(Qh, Kh, Vt, AO);

    gemm_o<<<dim3(Dm / 128, (Bsz * Sq) / 128), 256, 0, stream>>>(
        AO, WtAll + 3 * NW, bo, out);
}